// Round 2
// baseline (29193.564 us; speedup 1.0000x reference)
//
#include <hip/hip_runtime.h>
#include <hip/hip_bf16.h>

#define T_SEQ 543
#define B_TOT 2048

__device__ __forceinline__ float sigm(float x)   { return 1.0f / (1.0f + __expf(-x)); }
__device__ __forceinline__ float tanh_f(float x) { return 1.0f - 2.0f / (__expf(2.0f * x) + 1.0f); }

// Persistent GRU scan over one chunk of tc timesteps [t0, t0+tc).
// One block owns 8 batch rows. in layout: IN_IS_X ? x[B][T_SEQ][I] (global t)
// : chunk buffer [tc][B][I] (local t). hout: chunk buffer [tc][B][H] (ReLU'd).
// state: [B][H] raw h, loaded at chunk start (zeros if t0==0), stored at end.
template<int I, int H, bool WIH_LDS, bool WHH_LDS, bool IN_IS_X>
__global__ __launch_bounds__(512) void gru_scan_chunk(
    const float* __restrict__ in, const float* __restrict__ w_ih, const float* __restrict__ w_hh,
    const float* __restrict__ b_ih, const float* __restrict__ b_hh,
    float* __restrict__ state, float* __restrict__ hout, int t0, int tc)
{
    constexpr int G    = 3 * H;
    constexpr int IPAD = (I < 4) ? 4 : I;            // in_l row stride
    constexpr int IST  = ((I + 3) / 4) * 4 + 4;      // w_ih LDS row stride
    constexpr int HST  = H + 4;                      // w_hh LDS row stride

    __shared__ float in_l[8 * IPAD];
    __shared__ float h_l[2 * 8 * H];                 // double-buffered state
    __shared__ float bih_l[G];
    __shared__ float bhh_l[G];
    __shared__ float wih_l[WIH_LDS ? (G * IST) : 1];
    __shared__ float whh_l[WHH_LDS ? (G * HST) : 1];

    const int tid = threadIdx.x;
    const int Bb  = blockIdx.x * 8;

    for (int e = tid; e < G; e += 512) { bih_l[e] = b_ih[e]; bhh_l[e] = b_hh[e]; }
    if constexpr (WIH_LDS)
        for (int e = tid; e < G * I; e += 512) wih_l[(e / I) * IST + (e % I)] = w_ih[e];
    if constexpr (WHH_LDS)
        for (int e = tid; e < G * H; e += 512) whh_l[(e / H) * HST + (e % H)] = w_hh[e];
    // chunk-start state into buffer 0
    for (int e = tid; e < 8 * H; e += 512)
        h_l[e] = (t0 == 0) ? 0.0f : state[(size_t)(Bb + e / H) * H + (e % H)];
    __syncthreads();

    // thread -> (lane j, batch row b, half mo); each thread computes MPT outputs jo
    const int j  = tid & 31;
    const int b  = (tid >> 5) & 7;
    const int mo = tid >> 8;                          // 0..1
    constexpr int MPT = H / 64;                       // 1 (H=64) or 2 (H=128)

    int cur = 0;
    for (int tl = 0; tl < tc; ++tl) {
        // stage this step's input rows
        for (int e = tid; e < 8 * I; e += 512) {
            int bb = e / I, i = e - bb * I;
            size_t gi = IN_IS_X ? (((size_t)(Bb + bb) * T_SEQ + (t0 + tl)) * I + i)
                                : (((size_t)tl * B_TOT + Bb + bb) * I + i);
            in_l[bb * IPAD + i] = in[gi];
        }
        __syncthreads();

        const float* hrow = &h_l[cur * 8 * H + b * H];
        #pragma unroll
        for (int q = 0; q < MPT; ++q) {
            const int jo = j + 32 * (mo * MPT + q);
            float ar = bih_l[jo], az = bih_l[jo + H], an = bih_l[jo + 2 * H];
            float hr = bhh_l[jo], hz = bhh_l[jo + H], hn = bhh_l[jo + 2 * H];

            // ---- input contribution (xg) ----
            {
                const float *r0, *r1, *r2;
                if constexpr (WIH_LDS) {
                    r0 = &wih_l[jo * IST]; r1 = &wih_l[(jo + H) * IST]; r2 = &wih_l[(jo + 2 * H) * IST];
                } else {
                    r0 = &w_ih[(size_t)jo * I]; r1 = &w_ih[(size_t)(jo + H) * I]; r2 = &w_ih[(size_t)(jo + 2 * H) * I];
                }
                if constexpr (I == 3) {
                    const float x0 = in_l[b * IPAD], x1 = in_l[b * IPAD + 1], x2 = in_l[b * IPAD + 2];
                    ar += r0[0] * x0 + r0[1] * x1 + r0[2] * x2;
                    az += r1[0] * x0 + r1[1] * x1 + r1[2] * x2;
                    an += r2[0] * x0 + r2[1] * x1 + r2[2] * x2;
                } else {
                    #pragma unroll 4
                    for (int i = 0; i < I; i += 4) {
                        const float4 xv = *(const float4*)&in_l[b * IPAD + i];
                        const float4 a0 = *(const float4*)&r0[i];
                        const float4 a1 = *(const float4*)&r1[i];
                        const float4 a2 = *(const float4*)&r2[i];
                        ar += a0.x * xv.x + a0.y * xv.y + a0.z * xv.z + a0.w * xv.w;
                        az += a1.x * xv.x + a1.y * xv.y + a1.z * xv.z + a1.w * xv.w;
                        an += a2.x * xv.x + a2.y * xv.y + a2.z * xv.z + a2.w * xv.w;
                    }
                }
            }
            // ---- hidden contribution (hg) ----
            {
                const float *r0, *r1, *r2;
                if constexpr (WHH_LDS) {
                    r0 = &whh_l[jo * HST]; r1 = &whh_l[(jo + H) * HST]; r2 = &whh_l[(jo + 2 * H) * HST];
                } else {
                    r0 = &w_hh[(size_t)jo * H]; r1 = &w_hh[(size_t)(jo + H) * H]; r2 = &w_hh[(size_t)(jo + 2 * H) * H];
                }
                #pragma unroll 4
                for (int k = 0; k < H; k += 4) {
                    const float4 hv = *(const float4*)&hrow[k];
                    const float4 a0 = *(const float4*)&r0[k];
                    const float4 a1 = *(const float4*)&r1[k];
                    const float4 a2 = *(const float4*)&r2[k];
                    hr += a0.x * hv.x + a0.y * hv.y + a0.z * hv.z + a0.w * hv.w;
                    hz += a1.x * hv.x + a1.y * hv.y + a1.z * hv.z + a1.w * hv.w;
                    hn += a2.x * hv.x + a2.y * hv.y + a2.z * hv.z + a2.w * hv.w;
                }
            }
            const float r = sigm(ar + hr);
            const float z = sigm(az + hz);
            const float n = tanh_f(an + r * hn);
            const float hp = hrow[jo];
            const float hv = (1.0f - z) * n + z * hp;
            h_l[(cur ^ 1) * 8 * H + b * H + jo] = hv;
            hout[((size_t)tl * B_TOT + Bb + b) * H + jo] = fmaxf(hv, 0.0f);
        }
        cur ^= 1;
        __syncthreads();
    }

    // persist raw chunk-end state
    for (int e = tid; e < 8 * H; e += 512)
        state[(size_t)(Bb + e / H) * H + (e % H)] = h_l[cur * 8 * H + e];
}

// dense1 partial: out1[b][n] (+)= sum_{tl<tc} sum_k h3c[tl][b][k] * w1[n][(t0+tl)*64+k]
// (bias + relu applied later in dense23)
__global__ __launch_bounds__(512) void dense1_chunk(
    const float* __restrict__ h3c, const float* __restrict__ w1,
    float* __restrict__ out1, int t0, int tc)
{
    __shared__ float h_sl[8 * 64];        // [b][k]
    __shared__ float w_sl[64 * 65];       // [n][k], padded
    const int tid = threadIdx.x;
    const int Bb  = blockIdx.x * 8;
    const int n = tid & 63, bq = tid >> 6;  // 8 rows x 64 cols = 512 outputs
    float acc = (t0 == 0) ? 0.0f : out1[(size_t)(Bb + bq) * 64 + n];
    for (int tl = 0; tl < tc; ++tl) {
        __syncthreads();
        { int bb = tid >> 6, kk = tid & 63;
          h_sl[tid] = h3c[((size_t)tl * B_TOT + Bb + bb) * 64 + kk]; }
        #pragma unroll
        for (int qq = 0; qq < 8; ++qq) {
            int nn = (tid >> 6) + 8 * qq, kk = tid & 63;
            w_sl[nn * 65 + kk] = w1[(size_t)nn * (T_SEQ * 64) + (size_t)(t0 + tl) * 64 + kk];
        }
        __syncthreads();
        const float* hr = &h_sl[bq * 64];
        const float* wr = &w_sl[n * 65];
        #pragma unroll 8
        for (int kk = 0; kk < 64; ++kk) acc += hr[kk] * wr[kk];
    }
    out1[(size_t)(Bb + bq) * 64 + n] = acc;
}

// dense2 + dense3 fused, 32 batch rows per block; applies bias1+relu on load
__global__ __launch_bounds__(256) void dense23_kernel(
    const float* __restrict__ out1, const float* __restrict__ bd1,
    const float* __restrict__ w2, const float* __restrict__ bd2,
    const float* __restrict__ w3, const float* __restrict__ bd3, float* __restrict__ out)
{
    __shared__ float a_l[32 * 65];
    __shared__ float w2_l[32 * 65];
    __shared__ float o2_l[32 * 33];
    __shared__ float w3_l[250 * 33];
    const int tid = threadIdx.x;
    const int Rb  = blockIdx.x * 32;
    for (int e = tid; e < 32 * 64; e += 256) {
        int r = e >> 6, nn = e & 63;
        a_l[r * 65 + nn] = fmaxf(out1[(size_t)(Rb + r) * 64 + nn] + bd1[nn], 0.0f);
    }
    for (int e = tid; e < 32 * 64; e += 256) { int m = e >> 6, nn = e & 63; w2_l[m * 65 + nn] = w2[e]; }
    for (int e = tid; e < 250 * 32; e += 256) { int p = e >> 5, m = e & 31; w3_l[p * 33 + m] = w3[e]; }
    __syncthreads();
    for (int e = tid; e < 32 * 32; e += 256) {
        int r = e >> 5, m = e & 31;
        float acc = bd2[m];
        #pragma unroll 8
        for (int nn = 0; nn < 64; ++nn) acc += a_l[r * 65 + nn] * w2_l[m * 65 + nn];
        o2_l[r * 33 + m] = fmaxf(acc, 0.0f);
    }
    __syncthreads();
    for (int e = tid; e < 32 * 250; e += 256) {
        int r = e / 250, p = e - r * 250;
        float acc = bd3[p];
        #pragma unroll 8
        for (int m = 0; m < 32; ++m) acc += o2_l[r * 33 + m] * w3_l[p * 33 + m];
        out[(size_t)(Rb + r) * 250 + p] = fmaxf(acc, 0.0f);
    }
}

extern "C" void kernel_launch(void* const* d_in, const int* in_sizes, int n_in,
                              void* d_out, int out_size, void* d_ws, size_t ws_size,
                              hipStream_t stream) {
    const float* x     = (const float*)d_in[0];
    const float* w_ih1 = (const float*)d_in[1];
    const float* w_hh1 = (const float*)d_in[2];
    const float* b_ih1 = (const float*)d_in[3];
    const float* b_hh1 = (const float*)d_in[4];
    const float* w_ih2 = (const float*)d_in[5];
    const float* w_hh2 = (const float*)d_in[6];
    const float* b_ih2 = (const float*)d_in[7];
    const float* b_hh2 = (const float*)d_in[8];
    const float* w_ih3 = (const float*)d_in[9];
    const float* w_hh3 = (const float*)d_in[10];
    const float* b_ih3 = (const float*)d_in[11];
    const float* b_hh3 = (const float*)d_in[12];
    const float* w1    = (const float*)d_in[13];
    const float* bd1   = (const float*)d_in[14];
    const float* w2    = (const float*)d_in[15];
    const float* bd2   = (const float*)d_in[16];
    const float* w3    = (const float*)d_in[17];
    const float* bd3   = (const float*)d_in[18];
    float* out = (float*)d_out;

    // ---- workspace layout (all fp32), chunk size adapted to ws_size ----
    const size_t FB64  = (size_t)B_TOT * 64;
    const size_t FB128 = (size_t)B_TOT * 128;
    float* s1   = (float*)d_ws;             // [B][64]  raw h1 state
    float* s2   = s1 + FB64;                // [B][128] raw h2 state
    float* s3   = s2 + FB128;               // [B][64]  raw h3 state
    float* out1 = s3 + FB64;                // [B][64]  dense1 accumulator
    float* bufA = out1 + FB64;              // [TC][B][64]  (h1 chunk, reused for h3 chunk)
    const size_t fixed_bytes = (FB64 * 3 + FB128) * sizeof(float);
    const size_t per_t_bytes = (FB64 + FB128) * sizeof(float);

    long long avail = (long long)ws_size - (long long)fixed_bytes;
    long long tcl = (avail > 0) ? (avail / (long long)per_t_bytes) : 1;
    int TC = (int)((tcl < 1) ? 1 : ((tcl > T_SEQ) ? T_SEQ : tcl));
    float* bufB = bufA + (size_t)TC * FB64; // [TC][B][128] (h2 chunk)

    const int nch = (T_SEQ + TC - 1) / TC;
    for (int c = 0; c < nch; ++c) {
        const int t0 = c * TC;
        const int tc = (t0 + TC <= T_SEQ) ? TC : (T_SEQ - t0);
        hipLaunchKernelGGL((gru_scan_chunk<3, 64, true, true, true>),
                           dim3(B_TOT / 8), dim3(512), 0, stream,
                           x, w_ih1, w_hh1, b_ih1, b_hh1, s1, bufA, t0, tc);
        hipLaunchKernelGGL((gru_scan_chunk<64, 128, true, false, false>),
                           dim3(B_TOT / 8), dim3(512), 0, stream,
                           bufA, w_ih2, w_hh2, b_ih2, b_hh2, s2, bufB, t0, tc);
        hipLaunchKernelGGL((gru_scan_chunk<128, 64, true, true, false>),
                           dim3(B_TOT / 8), dim3(512), 0, stream,
                           bufB, w_ih3, w_hh3, b_ih3, b_hh3, s3, bufA, t0, tc);
        hipLaunchKernelGGL(dense1_chunk, dim3(B_TOT / 8), dim3(512), 0, stream,
                           bufA, w1, out1, t0, tc);
    }
    hipLaunchKernelGGL(dense23_kernel, dim3(B_TOT / 32), dim3(256), 0, stream,
                       out1, bd1, w2, bd2, w3, bd3, out);
}

// Round 3
// 17708.423 us; speedup vs baseline: 1.6486x; 1.6486x over previous
//
#include <hip/hip_runtime.h>

#define T_SEQ 543
#define B_TOT 2048

typedef _Float16 h2v __attribute__((ext_vector_type(2)));

#if defined(__has_builtin)
#if __has_builtin(__builtin_amdgcn_fdot2)
#define HAVE_FDOT2 1
#endif
#endif

__device__ __forceinline__ float sigm(float x)   { return 1.0f / (1.0f + __expf(-x)); }
__device__ __forceinline__ float tanh_f(float x) { return 1.0f - 2.0f / (__expf(2.0f * x) + 1.0f); }

__device__ __forceinline__ float dot2f(h2v a, h2v b, float c) {
#ifdef HAVE_FDOT2
    return __builtin_amdgcn_fdot2(a, b, c, false);
#else
    return c + (float)a.x * (float)b.x + (float)a.y * (float)b.y;
#endif
}

union U16 { uint4 u; h2v h[4]; };

__device__ __forceinline__ float dot16(uint4 w, uint4 x, float acc) {
    U16 a, bb; a.u = w; bb.u = x;
    acc = dot2f(a.h[0], bb.h[0], acc);
    acc = dot2f(a.h[1], bb.h[1], acc);
    acc = dot2f(a.h[2], bb.h[2], acc);
    acc = dot2f(a.h[3], bb.h[3], acc);
    return acc;
}

// ---- LDS byte offsets (total 161,920 <= 163,840) ----
#define OFF_WIH2 0        // k-major f16 [8 k16][384 rows] * 16B = 49152
#define OFF_WIH3 49152    // [16][192] = 49152
#define OFF_WHH1 98304    // [8][192]  = 24576
#define OFF_WHH3 122880   // [8][192]  = 24576
#define OFF_H1S  147456   // 2 bufs x 8 rows x 144B = 2304 (f16, 64+8 pad)
#define OFF_H2S  149760   // 2 x 8 x 272 = 4352     (f16, 128+8 pad)
#define OFF_H3S  154112   // 2 x 8 x 144 = 2304
#define OFF_H1R  156416   // 8 x 144 = 1152         (relu'd h1, f16)
#define OFF_H2R  157568   // 8 x 272 = 2176         (relu'd h2, f16)
#define OFF_H3F  159744   // 8 x 272 = 2176         (relu'd h3, f32, 64+4 pad)
#define SMEM_BYTES 161920

// Stage a [NR][KC*8] fp32 global matrix into k-major f16 LDS.
template<int NR, int KC>
__device__ __forceinline__ void stage_kmajor(unsigned char* smem, int off,
                                             const float* __restrict__ g, int tid) {
    uint4* dst = (uint4*)(smem + off);
    for (int e = tid; e < NR * KC; e += 512) {
        const int k16 = e / NR, row = e - k16 * NR;     // e == k16*NR + row
        const float* src = g + row * (KC * 8) + k16 * 8;
        float4 a = *(const float4*)src;
        float4 c = *(const float4*)(src + 4);
        U16 u;
        u.h[0].x = (_Float16)a.x; u.h[0].y = (_Float16)a.y;
        u.h[1].x = (_Float16)a.z; u.h[1].y = (_Float16)a.w;
        u.h[2].x = (_Float16)c.x; u.h[2].y = (_Float16)c.y;
        u.h[3].x = (_Float16)c.z; u.h[3].y = (_Float16)c.w;
        dst[e] = u.u;
    }
}

__global__ void cvt_whh2(const float* __restrict__ w, _Float16* __restrict__ o) {
    int i = blockIdx.x * 256 + threadIdx.x;
    if (i < 384 * 128) o[i] = (_Float16)w[i];
}

__global__ __launch_bounds__(512, 2) void gru_fused(
    const float* __restrict__ x,
    const float* __restrict__ w_ih1, const float* __restrict__ w_hh1,
    const float* __restrict__ b_ih1, const float* __restrict__ b_hh1,
    const float* __restrict__ w_ih2, const float* __restrict__ b_ih2, const float* __restrict__ b_hh2,
    const float* __restrict__ w_ih3, const float* __restrict__ w_hh3,
    const float* __restrict__ b_ih3, const float* __restrict__ b_hh3,
    const _Float16* __restrict__ whh2f,
    const float* __restrict__ w1, const float* __restrict__ bd1,
    const float* __restrict__ w2, const float* __restrict__ bd2,
    const float* __restrict__ w3, const float* __restrict__ bd3,
    float* __restrict__ out)
{
    __shared__ __align__(16) unsigned char smem[SMEM_BYTES];
    const int tid = threadIdx.x;
    const int Bb  = blockIdx.x * 8;
    const int b   = tid & 7;     // batch row within block
    const int jo  = tid >> 3;    // 0..63 output lane

    stage_kmajor<384, 8 >(smem, OFF_WIH2, w_ih2, tid);
    stage_kmajor<192, 16>(smem, OFF_WIH3, w_ih3, tid);
    stage_kmajor<192, 8 >(smem, OFF_WHH1, w_hh1, tid);
    stage_kmajor<192, 8 >(smem, OFF_WHH3, w_hh3, tid);
    for (int e = tid * 4; e < SMEM_BYTES - OFF_H1S; e += 512 * 4)
        *(float*)(smem + OFF_H1S + e) = 0.0f;

    // per-thread constant weights/biases in registers
    float wi1[9];
    #pragma unroll
    for (int g = 0; g < 3; ++g)
        #pragma unroll
        for (int i = 0; i < 3; ++i) wi1[g * 3 + i] = w_ih1[(jo + g * 64) * 3 + i];
    float bi1[3], bh1[3], bi3[3], bh3[3];
    #pragma unroll
    for (int g = 0; g < 3; ++g) {
        bi1[g] = b_ih1[jo + g * 64]; bh1[g] = b_hh1[jo + g * 64];
        bi3[g] = b_ih3[jo + g * 64]; bh3[g] = b_hh3[jo + g * 64];
    }
    float bi2[2][3], bh2[2][3];
    #pragma unroll
    for (int jj = 0; jj < 2; ++jj)
        #pragma unroll
        for (int g = 0; g < 3; ++g) {
            bi2[jj][g] = b_ih2[jo + jj * 64 + g * 128];
            bh2[jj][g] = b_hh2[jo + jj * 64 + g * 128];
        }

    float h1own = 0.f, h2own0 = 0.f, h2own1 = 0.f, h3own = 0.f, accd = 0.f;
    const float* xp = x + (size_t)(Bb + b) * T_SEQ * 3;

    __syncthreads();

    int cur = 0;
    for (int t = 0; t < T_SEQ; ++t) {
        const float x0 = xp[t * 3], x1 = xp[t * 3 + 1], x2v = xp[t * 3 + 2];

        // ---------- P1: layer 1 (I=3, H=64) ----------
        {
            uint4 hreg[8];
            const uint4* hp = (const uint4*)(smem + OFF_H1S + cur * 1152 + b * 144);
            #pragma unroll
            for (int i = 0; i < 8; ++i) hreg[i] = hp[i];
            float a0 = bh1[0], a1 = bh1[1], a2 = bh1[2];
            const uint4* wb = (const uint4*)(smem + OFF_WHH1);
            #pragma unroll
            for (int i = 0; i < 8; ++i) {
                a0 = dot16(wb[i * 192 + jo      ], hreg[i], a0);
                a1 = dot16(wb[i * 192 + jo +  64], hreg[i], a1);
                a2 = dot16(wb[i * 192 + jo + 128], hreg[i], a2);
            }
            const float xr = bi1[0] + wi1[0] * x0 + wi1[1] * x1 + wi1[2] * x2v;
            const float xz = bi1[1] + wi1[3] * x0 + wi1[4] * x1 + wi1[5] * x2v;
            const float xn = bi1[2] + wi1[6] * x0 + wi1[7] * x1 + wi1[8] * x2v;
            const float r = sigm(xr + a0);
            const float z = sigm(xz + a1);
            const float n = tanh_f(xn + r * a2);
            h1own = (1.f - z) * n + z * h1own;
            *(_Float16*)(smem + OFF_H1S + (cur ^ 1) * 1152 + b * 144 + jo * 2) = (_Float16)h1own;
            *(_Float16*)(smem + OFF_H1R + b * 144 + jo * 2) = (_Float16)fmaxf(h1own, 0.f);
        }
        __syncthreads();

        // ---------- P2: layer 2 (I=64, H=128), w_hh2 streamed f16 from global ----------
        {
            uint4 xreg[8], hreg[16];
            const uint4* xq = (const uint4*)(smem + OFF_H1R + b * 144);
            #pragma unroll
            for (int i = 0; i < 8; ++i) xreg[i] = xq[i];
            const uint4* hp = (const uint4*)(smem + OFF_H2S + cur * 2176 + b * 272);
            #pragma unroll
            for (int i = 0; i < 16; ++i) hreg[i] = hp[i];
            #pragma unroll
            for (int jj = 0; jj < 2; ++jj) {
                const int jo2 = jo + jj * 64;
                float a0 = bi2[jj][0], a1 = bi2[jj][1], a2 = bi2[jj][2];
                const uint4* wb = (const uint4*)(smem + OFF_WIH2);
                #pragma unroll
                for (int i = 0; i < 8; ++i) {
                    a0 = dot16(wb[i * 384 + jo2      ], xreg[i], a0);
                    a1 = dot16(wb[i * 384 + jo2 + 128], xreg[i], a1);
                    a2 = dot16(wb[i * 384 + jo2 + 256], xreg[i], a2);
                }
                float c0 = bh2[jj][0], c1 = bh2[jj][1], c2 = bh2[jj][2];
                const uint4* w0 = (const uint4*)(whh2f + (size_t)(jo2      ) * 128);
                const uint4* w1r = (const uint4*)(whh2f + (size_t)(jo2 + 128) * 128);
                const uint4* w2r = (const uint4*)(whh2f + (size_t)(jo2 + 256) * 128);
                #pragma unroll
                for (int i = 0; i < 16; ++i) {
                    c0 = dot16(w0[i],  hreg[i], c0);
                    c1 = dot16(w1r[i], hreg[i], c1);
                    c2 = dot16(w2r[i], hreg[i], c2);
                }
                const float r = sigm(a0 + c0);
                const float z = sigm(a1 + c1);
                const float n = tanh_f(a2 + r * c2);
                float hnew = (jj == 0) ? ((1.f - z) * n + z * h2own0)
                                       : ((1.f - z) * n + z * h2own1);
                if (jj == 0) h2own0 = hnew; else h2own1 = hnew;
                *(_Float16*)(smem + OFF_H2S + (cur ^ 1) * 2176 + b * 272 + jo2 * 2) = (_Float16)hnew;
                *(_Float16*)(smem + OFF_H2R + b * 272 + jo2 * 2) = (_Float16)fmaxf(hnew, 0.f);
            }
        }
        __syncthreads();

        // ---------- P3: layer 3 (I=128, H=64) ----------
        {
            uint4 xreg[16], hreg[8];
            const uint4* xq = (const uint4*)(smem + OFF_H2R + b * 272);
            #pragma unroll
            for (int i = 0; i < 16; ++i) xreg[i] = xq[i];
            const uint4* hp = (const uint4*)(smem + OFF_H3S + cur * 1152 + b * 144);
            #pragma unroll
            for (int i = 0; i < 8; ++i) hreg[i] = hp[i];
            float a0 = bi3[0], a1 = bi3[1], a2 = bi3[2];
            const uint4* wb = (const uint4*)(smem + OFF_WIH3);
            #pragma unroll
            for (int i = 0; i < 16; ++i) {
                a0 = dot16(wb[i * 192 + jo      ], xreg[i], a0);
                a1 = dot16(wb[i * 192 + jo +  64], xreg[i], a1);
                a2 = dot16(wb[i * 192 + jo + 128], xreg[i], a2);
            }
            float c0 = bh3[0], c1 = bh3[1], c2 = bh3[2];
            const uint4* wh = (const uint4*)(smem + OFF_WHH3);
            #pragma unroll
            for (int i = 0; i < 8; ++i) {
                c0 = dot16(wh[i * 192 + jo      ], hreg[i], c0);
                c1 = dot16(wh[i * 192 + jo +  64], hreg[i], c1);
                c2 = dot16(wh[i * 192 + jo + 128], hreg[i], c2);
            }
            const float r = sigm(a0 + c0);
            const float z = sigm(a1 + c1);
            const float n = tanh_f(a2 + r * c2);
            h3own = (1.f - z) * n + z * h3own;
            *(_Float16*)(smem + OFF_H3S + (cur ^ 1) * 1152 + b * 144 + jo * 2) = (_Float16)h3own;
            *(float*)(smem + OFF_H3F + b * 272 + jo * 4) = fmaxf(h3own, 0.f);
        }
        __syncthreads();

        // ---------- P4: dense1 partial (register accumulation, no sync needed after) ----------
        {
            const float* hr = (const float*)(smem + OFF_H3F + b * 272);
            const float* wp = w1 + (size_t)jo * (T_SEQ * 64) + t * 64;
            #pragma unroll
            for (int i = 0; i < 16; ++i) {
                float4 hv = *(const float4*)(hr + i * 4);
                float4 wv = *(const float4*)(wp + i * 4);
                accd += hv.x * wv.x + hv.y * wv.y + hv.z * wv.z + hv.w * wv.w;
            }
        }
        cur ^= 1;
    }

    // ---------- head: dense1 bias+relu -> dense2 -> dense3 (reuse LDS) ----------
    __syncthreads();                       // weights region no longer needed
    float* o1 = (float*)smem;              // [8][68] f32
    o1[b * 68 + jo] = fmaxf(accd + bd1[jo], 0.f);
    __syncthreads();
    float* o2 = (float*)(smem + 4096);     // [8][36] f32
    if (tid < 256) {
        const int bb = tid & 7, m = tid >> 3;      // m 0..31
        float acc = bd2[m];
        const float* w2p = w2 + m * 64;
        const float* o1p = o1 + bb * 68;
        #pragma unroll
        for (int i = 0; i < 16; ++i) {
            float4 a = *(const float4*)(o1p + i * 4);
            float4 wv = *(const float4*)(w2p + i * 4);
            acc += a.x * wv.x + a.y * wv.y + a.z * wv.z + a.w * wv.w;
        }
        o2[bb * 36 + m] = fmaxf(acc, 0.f);
    }
    __syncthreads();
    for (int e = tid; e < 8 * 250; e += 512) {
        const int bb = e / 250, p = e - bb * 250;
        float acc = bd3[p];
        const float* w3p = w3 + p * 32;
        const float* o2p = o2 + bb * 36;
        #pragma unroll
        for (int i = 0; i < 8; ++i) {
            float4 a = *(const float4*)(o2p + i * 4);
            float4 wv = *(const float4*)(w3p + i * 4);
            acc += a.x * wv.x + a.y * wv.y + a.z * wv.z + a.w * wv.w;
        }
        out[(size_t)(Bb + bb) * 250 + p] = fmaxf(acc, 0.f);
    }
}

extern "C" void kernel_launch(void* const* d_in, const int* in_sizes, int n_in,
                              void* d_out, int out_size, void* d_ws, size_t ws_size,
                              hipStream_t stream) {
    const float* x     = (const float*)d_in[0];
    const float* w_ih1 = (const float*)d_in[1];
    const float* w_hh1 = (const float*)d_in[2];
    const float* b_ih1 = (const float*)d_in[3];
    const float* b_hh1 = (const float*)d_in[4];
    const float* w_ih2 = (const float*)d_in[5];
    const float* w_hh2 = (const float*)d_in[6];
    const float* b_ih2 = (const float*)d_in[7];
    const float* b_hh2 = (const float*)d_in[8];
    const float* w_ih3 = (const float*)d_in[9];
    const float* w_hh3 = (const float*)d_in[10];
    const float* b_ih3 = (const float*)d_in[11];
    const float* b_hh3 = (const float*)d_in[12];
    const float* w1    = (const float*)d_in[13];
    const float* bd1   = (const float*)d_in[14];
    const float* w2    = (const float*)d_in[15];
    const float* bd2   = (const float*)d_in[16];
    const float* w3    = (const float*)d_in[17];
    const float* bd3   = (const float*)d_in[18];
    float* out = (float*)d_out;

    _Float16* whh2f = (_Float16*)d_ws;   // 384*128*2 = 98,304 bytes

    hipLaunchKernelGGL(cvt_whh2, dim3(192), dim3(256), 0, stream, w_hh2, whh2f);
    hipLaunchKernelGGL(gru_fused, dim3(B_TOT / 8), dim3(512), 0, stream,
                       x, w_ih1, w_hh1, b_ih1, b_hh1,
                       w_ih2, b_ih2, b_hh2,
                       w_ih3, w_hh3, b_ih3, b_hh3,
                       whh2f, w1, bd1, w2, bd2, w3, bd3, out);
}

// Round 4
// 2783.726 us; speedup vs baseline: 10.4872x; 6.3614x over previous
//
#include <hip/hip_runtime.h>

#define T_SEQ 543
#define B_TOT 2048

typedef _Float16 f16;
typedef f16   f16x8 __attribute__((ext_vector_type(8)));
typedef f16   f16x2 __attribute__((ext_vector_type(2)));
typedef float f32x4 __attribute__((ext_vector_type(4)));

#if defined(__has_builtin)
#if __has_builtin(__builtin_amdgcn_fdot2)
#define HAVE_FDOT2 1
#endif
#endif

__device__ __forceinline__ float sigm(float x)   { return 1.0f / (1.0f + __expf(-x)); }
__device__ __forceinline__ float tanh_f(float x) { return 1.0f - 2.0f / (__expf(2.0f * x) + 1.0f); }

__device__ __forceinline__ f32x4 mfma16(f16x8 a, f16x8 b, f32x4 c) {
    return __builtin_amdgcn_mfma_f32_16x16x32_f16(a, b, c, 0, 0, 0);
}

__device__ __forceinline__ float dot2f(f16x2 a, f16x2 b, float c) {
#ifdef HAVE_FDOT2
    return __builtin_amdgcn_fdot2(a, b, c, false);
#else
    return c + (float)a.x * (float)b.x + (float)a.y * (float)b.y;
#endif
}

union U8 { f16x8 v; f16x2 h[4]; };
__device__ __forceinline__ float dot8(f16x8 a, f16x8 b, float c) {
    U8 A, B; A.v = a; B.v = b;
    c = dot2f(A.h[0], B.h[0], c); c = dot2f(A.h[1], B.h[1], c);
    c = dot2f(A.h[2], B.h[2], c); c = dot2f(A.h[3], B.h[3], c);
    return c;
}

// B-fragment: lane holds w[nrow][k0..k0+8) as f16x8 (row-major fp32 source)
__device__ __forceinline__ f16x8 loadB(const float* __restrict__ g, int nrow, int ldk, int k0) {
    const float* p = g + (size_t)nrow * ldk + k0;
    float4 a = *(const float4*)p;
    float4 b = *(const float4*)(p + 4);
    f16x8 r;
    r[0] = (f16)a.x; r[1] = (f16)a.y; r[2] = (f16)a.z; r[3] = (f16)a.w;
    r[4] = (f16)b.x; r[5] = (f16)b.y; r[6] = (f16)b.z; r[7] = (f16)b.w;
    return r;
}

// ---- LDS layout (bytes) ----
#define L_H1S 0        // 2 bufs x [16][64] f16 = 4096   (raw h1)
#define L_H2S 4096     // 2 x [16][128] f16   = 8192     (raw h2)
#define L_H3S 12288    // 2 x [16][64] f16    = 4096     (raw h3)
#define L_H1R 16384    // [16][64] f16        = 2048     (relu h1)
#define L_H2R 18432    // [16][128] f16       = 4096     (relu h2)
#define L_H3R 22528    // [16][64] f16        = 2048     (relu h3)
#define L_X1  24576    // [16] x float4       = 256      (x(t), col3=0)
#define SMEM_T 24832

// XOR-swizzled LDS accessors (swizzle spreads row-strided b128 reads over banks)
__device__ __forceinline__ f16x8 ldsA(const unsigned char* sm, int base, int stride, int row, int kByte) {
    int off = (base + row * stride + kByte) ^ ((row & 7) << 4);
    return *(const f16x8*)(sm + off);
}
__device__ __forceinline__ void stH(unsigned char* sm, int base, int stride, int row, int col, f16 v) {
    int off = (base + row * stride + col * 2) ^ ((row & 7) << 4);
    *(f16*)(sm + off) = v;
}

__global__ void cvt_f16(const float* __restrict__ s, f16* __restrict__ d, int n) {
    int i = blockIdx.x * 256 + threadIdx.x;
    if (i < n) d[i] = (f16)s[i];
}

template<bool W1H>
__global__ __launch_bounds__(512, 2) void gru_fused(
    const float* __restrict__ x,
    const float* __restrict__ w_ih1, const float* __restrict__ w_hh1,
    const float* __restrict__ b_ih1, const float* __restrict__ b_hh1,
    const float* __restrict__ w_ih2, const float* __restrict__ w_hh2,
    const float* __restrict__ b_ih2, const float* __restrict__ b_hh2,
    const float* __restrict__ w_ih3, const float* __restrict__ w_hh3,
    const float* __restrict__ b_ih3, const float* __restrict__ b_hh3,
    const f16* __restrict__ w1h, const float* __restrict__ w1, const float* __restrict__ bd1,
    const float* __restrict__ w2, const float* __restrict__ bd2,
    const float* __restrict__ w3, const float* __restrict__ bd3,
    float* __restrict__ out)
{
    __shared__ __align__(16) unsigned char sm[SMEM_T];
    const int tid = threadIdx.x;
    const int Bb  = blockIdx.x * 8;
    const int wv  = tid >> 6;      // wave 0..7
    const int l   = tid & 63;
    const int lc  = l & 15;        // M/N index within fragment
    const int lr  = l >> 4;        // k-group / row-group

    // zero all LDS once (pad rows 8-15 must stay zero forever)
    for (int e = tid * 4; e < SMEM_T; e += 512 * 4) *(float*)(sm + e) = 0.0f;
    // stage x(t=0), rows 0-7 only
    if (tid < 24) {
        int row = tid / 3, c = tid - row * 3;
        *(float*)(sm + L_X1 + row * 16 + c * 4) = x[(size_t)(Bb + row) * T_SEQ * 3 + c];
    }

    // ---- persistent weight fragments in VGPRs ----
    f16x8 b1h[3][2];               // waves 0-3: w_hh1 [192][64]
    f16x8 b3x[3][4], b3h[3][2];    // waves 4-7: w_ih3 [192][128], w_hh3 [192][64]
    f16x8 b2x[3][2], b2h[3][4];    // all waves: w_ih2 [384][64], w_hh2 [384][128]
    float wi1[9];
    float bs1r = 0, bs1z = 0, bi1n = 0, bh1n = 0;
    float bs3r = 0, bs3z = 0, bi3n = 0, bh3n = 0;

    const int cj = (wv & 3) * 16 + lc;    // h-col for L1/L3 phases
    if (wv < 4) {
        #pragma unroll
        for (int g = 0; g < 3; ++g) {
            #pragma unroll
            for (int kt = 0; kt < 2; ++kt)
                b1h[g][kt] = loadB(w_hh1, g * 64 + cj, 64, kt * 32 + lr * 8);
        }
        bs1r = b_ih1[cj] + b_hh1[cj];
        bs1z = b_ih1[cj + 64] + b_hh1[cj + 64];
        bi1n = b_ih1[cj + 128]; bh1n = b_hh1[cj + 128];
        #pragma unroll
        for (int g = 0; g < 3; ++g)
            #pragma unroll
            for (int i = 0; i < 3; ++i) wi1[g * 3 + i] = w_ih1[(cj + g * 64) * 3 + i];
    } else {
        #pragma unroll
        for (int g = 0; g < 3; ++g) {
            #pragma unroll
            for (int kt = 0; kt < 4; ++kt)
                b3x[g][kt] = loadB(w_ih3, g * 64 + cj, 128, kt * 32 + lr * 8);
            #pragma unroll
            for (int kt = 0; kt < 2; ++kt)
                b3h[g][kt] = loadB(w_hh3, g * 64 + cj, 64, kt * 32 + lr * 8);
        }
        bs3r = b_ih3[cj] + b_hh3[cj];
        bs3z = b_ih3[cj + 64] + b_hh3[cj + 64];
        bi3n = b_ih3[cj + 128]; bh3n = b_hh3[cj + 128];
    }
    const int cj2 = wv * 16 + lc;         // h-col for L2 phase
    #pragma unroll
    for (int g = 0; g < 3; ++g) {
        #pragma unroll
        for (int kt = 0; kt < 2; ++kt)
            b2x[g][kt] = loadB(w_ih2, g * 128 + cj2, 64, kt * 32 + lr * 8);
        #pragma unroll
        for (int kt = 0; kt < 4; ++kt)
            b2h[g][kt] = loadB(w_hh2, g * 128 + cj2, 128, kt * 32 + lr * 8);
    }
    const float bs2r = b_ih2[cj2] + b_hh2[cj2];
    const float bs2z = b_ih2[cj2 + 128] + b_hh2[cj2 + 128];
    const float bi2n = b_ih2[cj2 + 256], bh2n = b_hh2[cj2 + 256];

    // recurrent state in registers (D-frag layout: col=lc, rows lr*4+i)
    float h1o[4] = {0, 0, 0, 0}, h2o[4] = {0, 0, 0, 0}, h3o[4] = {0, 0, 0, 0};
    float accd = 0.0f;
    const int bq = tid & 7, jo = tid >> 3;   // P4 mapping

    int cur = 0;
    #pragma unroll 1
    for (int t = 0; t < T_SEQ; ++t) {
        const int nxt = cur ^ 1;
        __syncthreads();   // x(t) staged; h*s[cur] complete

        // ---------- P1: layer 1 (waves 0-3) ----------
        if (wv < 4) {
            f16x8 ah0 = ldsA(sm, L_H1S + cur * 2048, 128, lc, lr * 16);
            f16x8 ah1 = ldsA(sm, L_H1S + cur * 2048, 128, lc, 64 + lr * 16);
            f32x4 aR = {0,0,0,0}, aZ = {0,0,0,0}, aN = {0,0,0,0};
            aR = mfma16(ah0, b1h[0][0], aR); aR = mfma16(ah1, b1h[0][1], aR);
            aZ = mfma16(ah0, b1h[1][0], aZ); aZ = mfma16(ah1, b1h[1][1], aZ);
            aN = mfma16(ah0, b1h[2][0], aN); aN = mfma16(ah1, b1h[2][1], aN);
            #pragma unroll
            for (int i = 0; i < 4; ++i) {
                const int row = lr * 4 + i;
                float4 xv = *(const float4*)(sm + L_X1 + row * 16);
                float xgr = wi1[0] * xv.x + wi1[1] * xv.y + wi1[2] * xv.z;
                float xgz = wi1[3] * xv.x + wi1[4] * xv.y + wi1[5] * xv.z;
                float xgn = wi1[6] * xv.x + wi1[7] * xv.y + wi1[8] * xv.z;
                float r = sigm(aR[i] + xgr + bs1r);
                float z = sigm(aZ[i] + xgz + bs1z);
                float n = tanh_f((xgn + bi1n) + r * (aN[i] + bh1n));
                float hv = (1.f - z) * n + z * h1o[i];
                h1o[i] = hv;
                if (l < 32) {
                    stH(sm, L_H1S + nxt * 2048, 128, row, cj, (f16)hv);
                    stH(sm, L_H1R, 128, row, cj, (f16)fmaxf(hv, 0.f));
                }
            }
        }
        __syncthreads();

        // ---------- P2: layer 2 (all 8 waves) ----------
        {
            f16x8 ax0 = ldsA(sm, L_H1R, 128, lc, lr * 16);
            f16x8 ax1 = ldsA(sm, L_H1R, 128, lc, 64 + lr * 16);
            f16x8 ah0 = ldsA(sm, L_H2S + cur * 4096, 256, lc, lr * 16);
            f16x8 ah1 = ldsA(sm, L_H2S + cur * 4096, 256, lc, 64 + lr * 16);
            f16x8 ah2 = ldsA(sm, L_H2S + cur * 4096, 256, lc, 128 + lr * 16);
            f16x8 ah3 = ldsA(sm, L_H2S + cur * 4096, 256, lc, 192 + lr * 16);
            f32x4 aR = {0,0,0,0}, aZ = {0,0,0,0}, aXn = {0,0,0,0}, aHn = {0,0,0,0};
            aR = mfma16(ax0, b2x[0][0], aR); aR = mfma16(ax1, b2x[0][1], aR);
            aR = mfma16(ah0, b2h[0][0], aR); aR = mfma16(ah1, b2h[0][1], aR);
            aR = mfma16(ah2, b2h[0][2], aR); aR = mfma16(ah3, b2h[0][3], aR);
            aZ = mfma16(ax0, b2x[1][0], aZ); aZ = mfma16(ax1, b2x[1][1], aZ);
            aZ = mfma16(ah0, b2h[1][0], aZ); aZ = mfma16(ah1, b2h[1][1], aZ);
            aZ = mfma16(ah2, b2h[1][2], aZ); aZ = mfma16(ah3, b2h[1][3], aZ);
            aXn = mfma16(ax0, b2x[2][0], aXn); aXn = mfma16(ax1, b2x[2][1], aXn);
            aHn = mfma16(ah0, b2h[2][0], aHn); aHn = mfma16(ah1, b2h[2][1], aHn);
            aHn = mfma16(ah2, b2h[2][2], aHn); aHn = mfma16(ah3, b2h[2][3], aHn);
            #pragma unroll
            for (int i = 0; i < 4; ++i) {
                const int row = lr * 4 + i;
                float r = sigm(aR[i] + bs2r);
                float z = sigm(aZ[i] + bs2z);
                float n = tanh_f((aXn[i] + bi2n) + r * (aHn[i] + bh2n));
                float hv = (1.f - z) * n + z * h2o[i];
                h2o[i] = hv;
                if (l < 32) {
                    stH(sm, L_H2S + nxt * 4096, 256, row, cj2, (f16)hv);
                    stH(sm, L_H2R, 256, row, cj2, (f16)fmaxf(hv, 0.f));
                }
            }
        }
        __syncthreads();

        // ---------- P3: layer 3 (waves 4-7) ----------
        if (wv >= 4) {
            f16x8 ax0 = ldsA(sm, L_H2R, 256, lc, lr * 16);
            f16x8 ax1 = ldsA(sm, L_H2R, 256, lc, 64 + lr * 16);
            f16x8 ax2 = ldsA(sm, L_H2R, 256, lc, 128 + lr * 16);
            f16x8 ax3 = ldsA(sm, L_H2R, 256, lc, 192 + lr * 16);
            f16x8 ah0 = ldsA(sm, L_H3S + cur * 2048, 128, lc, lr * 16);
            f16x8 ah1 = ldsA(sm, L_H3S + cur * 2048, 128, lc, 64 + lr * 16);
            f32x4 aR = {0,0,0,0}, aZ = {0,0,0,0}, aXn = {0,0,0,0}, aHn = {0,0,0,0};
            aR = mfma16(ax0, b3x[0][0], aR); aR = mfma16(ax1, b3x[0][1], aR);
            aR = mfma16(ax2, b3x[0][2], aR); aR = mfma16(ax3, b3x[0][3], aR);
            aR = mfma16(ah0, b3h[0][0], aR); aR = mfma16(ah1, b3h[0][1], aR);
            aZ = mfma16(ax0, b3x[1][0], aZ); aZ = mfma16(ax1, b3x[1][1], aZ);
            aZ = mfma16(ax2, b3x[1][2], aZ); aZ = mfma16(ax3, b3x[1][3], aZ);
            aZ = mfma16(ah0, b3h[1][0], aZ); aZ = mfma16(ah1, b3h[1][1], aZ);
            aXn = mfma16(ax0, b3x[2][0], aXn); aXn = mfma16(ax1, b3x[2][1], aXn);
            aXn = mfma16(ax2, b3x[2][2], aXn); aXn = mfma16(ax3, b3x[2][3], aXn);
            aHn = mfma16(ah0, b3h[2][0], aHn); aHn = mfma16(ah1, b3h[2][1], aHn);
            #pragma unroll
            for (int i = 0; i < 4; ++i) {
                const int row = lr * 4 + i;
                float r = sigm(aR[i] + bs3r);
                float z = sigm(aZ[i] + bs3z);
                float n = tanh_f((aXn[i] + bi3n) + r * (aHn[i] + bh3n));
                float hv = (1.f - z) * n + z * h3o[i];
                h3o[i] = hv;
                if (l < 32) {
                    stH(sm, L_H3S + nxt * 2048, 128, row, cj, (f16)hv);
                    stH(sm, L_H3R, 128, row, cj, (f16)fmaxf(hv, 0.f));
                }
            }
        }
        __syncthreads();

        // ---------- P4: dense1 partial + stage x(t+1) ----------
        if (tid < 24) {
            int row = tid / 3, c = tid - row * 3;
            int tn = (t + 1 < T_SEQ) ? t + 1 : t;
            *(float*)(sm + L_X1 + row * 16 + c * 4) =
                x[(size_t)(Bb + row) * T_SEQ * 3 + (size_t)tn * 3 + c];
        }
        {
            #pragma unroll
            for (int i = 0; i < 8; ++i) {
                int off = (L_H3R + bq * 128 + i * 16) ^ ((bq & 7) << 4);
                f16x8 hv = *(const f16x8*)(sm + off);
                if (W1H) {
                    f16x8 wv8 = *(const f16x8*)(w1h + (size_t)jo * (T_SEQ * 64) + (size_t)t * 64 + i * 8);
                    accd = dot8(hv, wv8, accd);
                } else {
                    const float* wp = w1 + (size_t)jo * (T_SEQ * 64) + (size_t)t * 64 + i * 8;
                    float4 a = *(const float4*)wp;
                    float4 b = *(const float4*)(wp + 4);
                    accd += (float)hv[0] * a.x + (float)hv[1] * a.y + (float)hv[2] * a.z + (float)hv[3] * a.w
                          + (float)hv[4] * b.x + (float)hv[5] * b.y + (float)hv[6] * b.z + (float)hv[7] * b.w;
                }
            }
        }
        cur ^= 1;
    }

    // ---------- head: dense1 bias+relu -> dense2 -> dense3 ----------
    __syncthreads();
    float* o1 = (float*)sm;              // [8][68]
    o1[bq * 68 + jo] = fmaxf(accd + bd1[jo], 0.f);
    __syncthreads();
    float* o2 = (float*)(sm + 4096);     // [8][36]
    if (tid < 256) {
        const int bb = tid & 7, m = tid >> 3;
        float acc = bd2[m];
        const float* w2p = w2 + m * 64;
        const float* o1p = o1 + bb * 68;
        #pragma unroll
        for (int i = 0; i < 16; ++i) {
            float4 a = *(const float4*)(o1p + i * 4);
            float4 wv = *(const float4*)(w2p + i * 4);
            acc += a.x * wv.x + a.y * wv.y + a.z * wv.z + a.w * wv.w;
        }
        o2[bb * 36 + m] = fmaxf(acc, 0.f);
    }
    __syncthreads();
    for (int e = tid; e < 8 * 250; e += 512) {
        const int bb = e / 250, p = e - bb * 250;
        float acc = bd3[p];
        const float* w3p = w3 + p * 32;
        const float* o2p = o2 + bb * 36;
        #pragma unroll
        for (int i = 0; i < 8; ++i) {
            float4 a = *(const float4*)(o2p + i * 4);
            float4 wv = *(const float4*)(w3p + i * 4);
            acc += a.x * wv.x + a.y * wv.y + a.z * wv.z + a.w * wv.w;
        }
        out[(size_t)(Bb + bb) * 250 + p] = fmaxf(acc, 0.f);
    }
}

extern "C" void kernel_launch(void* const* d_in, const int* in_sizes, int n_in,
                              void* d_out, int out_size, void* d_ws, size_t ws_size,
                              hipStream_t stream) {
    const float* x     = (const float*)d_in[0];
    const float* w_ih1 = (const float*)d_in[1];
    const float* w_hh1 = (const float*)d_in[2];
    const float* b_ih1 = (const float*)d_in[3];
    const float* b_hh1 = (const float*)d_in[4];
    const float* w_ih2 = (const float*)d_in[5];
    const float* w_hh2 = (const float*)d_in[6];
    const float* b_ih2 = (const float*)d_in[7];
    const float* b_hh2 = (const float*)d_in[8];
    const float* w_ih3 = (const float*)d_in[9];
    const float* w_hh3 = (const float*)d_in[10];
    const float* b_ih3 = (const float*)d_in[11];
    const float* b_hh3 = (const float*)d_in[12];
    const float* w1    = (const float*)d_in[13];
    const float* bd1   = (const float*)d_in[14];
    const float* w2    = (const float*)d_in[15];
    const float* bd2   = (const float*)d_in[16];
    const float* w3    = (const float*)d_in[17];
    const float* bd3   = (const float*)d_in[18];
    float* out = (float*)d_out;

    const int n1 = 64 * T_SEQ * 64;                 // w1 elements
    const bool useF16 = ws_size >= (size_t)n1 * sizeof(f16);
    f16* w1h = (f16*)d_ws;

    if (useF16) {
        hipLaunchKernelGGL(cvt_f16, dim3((n1 + 255) / 256), dim3(256), 0, stream, w1, w1h, n1);
        hipLaunchKernelGGL((gru_fused<true>), dim3(B_TOT / 8), dim3(512), 0, stream,
                           x, w_ih1, w_hh1, b_ih1, b_hh1, w_ih2, w_hh2, b_ih2, b_hh2,
                           w_ih3, w_hh3, b_ih3, b_hh3,
                           w1h, w1, bd1, w2, bd2, w3, bd3, out);
    } else {
        hipLaunchKernelGGL((gru_fused<false>), dim3(B_TOT / 8), dim3(512), 0, stream,
                           x, w_ih1, w_hh1, b_ih1, b_hh1, w_ih2, w_hh2, b_ih2, b_hh2,
                           w_ih3, w_hh3, b_ih3, b_hh3,
                           w1h, w1, bd1, w2, bd2, w3, bd3, out);
    }
}

// Round 5
// 2073.690 us; speedup vs baseline: 14.0781x; 1.3424x over previous
//
#include <hip/hip_runtime.h>

#define T_SEQ 543
#define B_TOT 2048

typedef _Float16 f16;
typedef f16   f16x8 __attribute__((ext_vector_type(8)));
typedef f16   f16x2 __attribute__((ext_vector_type(2)));
typedef float f32x4 __attribute__((ext_vector_type(4)));

#if defined(__has_builtin)
#if __has_builtin(__builtin_amdgcn_fdot2)
#define HAVE_FDOT2 1
#endif
#if __has_builtin(__builtin_amdgcn_rcpf)
#define RCP(x) __builtin_amdgcn_rcpf(x)
#endif
#endif
#ifndef RCP
#define RCP(x) (1.0f / (x))
#endif

// v_rcp-based gates: ~1 ulp vs IEEE divide; avoids v_div_scale/fmas/fixup bloat
__device__ __forceinline__ float sigm(float x)   { return RCP(1.0f + __expf(-x)); }
__device__ __forceinline__ float tanh_f(float x) { return fmaf(-2.0f, RCP(__expf(2.0f * x) + 1.0f), 1.0f); }

__device__ __forceinline__ f32x4 mfma16(f16x8 a, f16x8 b, f32x4 c) {
    return __builtin_amdgcn_mfma_f32_16x16x32_f16(a, b, c, 0, 0, 0);
}

__device__ __forceinline__ float dot2f(f16x2 a, f16x2 b, float c) {
#ifdef HAVE_FDOT2
    return __builtin_amdgcn_fdot2(a, b, c, false);
#else
    return c + (float)a.x * (float)b.x + (float)a.y * (float)b.y;
#endif
}

union U8 { f16x8 v; f16x2 h[4]; };
__device__ __forceinline__ float dot8(f16x8 a, f16x8 b, float c) {
    U8 A, B; A.v = a; B.v = b;
    c = dot2f(A.h[0], B.h[0], c); c = dot2f(A.h[1], B.h[1], c);
    c = dot2f(A.h[2], B.h[2], c); c = dot2f(A.h[3], B.h[3], c);
    return c;
}

// B-fragment: lane holds w[nrow][k0..k0+8) as f16x8 (row-major fp32 source)
__device__ __forceinline__ f16x8 loadB(const float* __restrict__ g, int nrow, int ldk, int k0) {
    const float* p = g + (size_t)nrow * ldk + k0;
    float4 a = *(const float4*)p;
    float4 b = *(const float4*)(p + 4);
    f16x8 r;
    r[0] = (f16)a.x; r[1] = (f16)a.y; r[2] = (f16)a.z; r[3] = (f16)a.w;
    r[4] = (f16)b.x; r[5] = (f16)b.y; r[6] = (f16)b.z; r[7] = (f16)b.w;
    return r;
}

// ---- LDS layout (bytes) ----
#define L_H1S 0        // 2 bufs x [16][64] f16 = 4096   (raw h1)
#define L_H2S 4096     // 2 x [16][128] f16   = 8192     (raw h2)
#define L_H3S 12288    // 2 x [16][64] f16    = 4096     (raw h3)
#define L_H1R 16384    // [16][64] f16        = 2048     (relu h1)
#define L_H2R 18432    // [16][128] f16       = 4096     (relu h2)
#define L_H3R 22528    // 2 bufs x [16][64] f16 = 4096   (relu h3, dbuf for P4 overlap)
#define L_X1  26624    // [16] x float4       = 256      (x(t), col3=0)
#define SMEM_T 26880

// XOR-swizzled LDS accessors (spread row-strided b128 reads over banks)
__device__ __forceinline__ f16x8 ldsA(const unsigned char* sm, int base, int stride, int row, int kByte) {
    int off = (base + row * stride + kByte) ^ ((row & 7) << 4);
    return *(const f16x8*)(sm + off);
}
__device__ __forceinline__ void stH(unsigned char* sm, int base, int stride, int row, int col, f16 v) {
    int off = (base + row * stride + col * 2) ^ ((row & 7) << 4);
    *(f16*)(sm + off) = v;
}

__global__ void cvt_f16(const float* __restrict__ s, f16* __restrict__ d, int n) {
    int i = blockIdx.x * 256 + threadIdx.x;
    if (i < n) d[i] = (f16)s[i];
}

template<bool W1H>
__global__ __launch_bounds__(512, 2) void gru_fused(
    const float* __restrict__ x,
    const float* __restrict__ w_ih1, const float* __restrict__ w_hh1,
    const float* __restrict__ b_ih1, const float* __restrict__ b_hh1,
    const float* __restrict__ w_ih2, const float* __restrict__ w_hh2,
    const float* __restrict__ b_ih2, const float* __restrict__ b_hh2,
    const float* __restrict__ w_ih3, const float* __restrict__ w_hh3,
    const float* __restrict__ b_ih3, const float* __restrict__ b_hh3,
    const f16* __restrict__ w1h, const float* __restrict__ w1, const float* __restrict__ bd1,
    const float* __restrict__ w2, const float* __restrict__ bd2,
    const float* __restrict__ w3, const float* __restrict__ bd3,
    float* __restrict__ out)
{
    __shared__ __align__(16) unsigned char sm[SMEM_T];
    const int tid = threadIdx.x;
    const int Bb  = blockIdx.x * 8;
    const int wv  = tid >> 6;      // wave 0..7
    const int l   = tid & 63;
    const int lc  = l & 15;        // M/N index within fragment
    const int lr  = l >> 4;        // k-group / row-group

    // zero all LDS once (pad rows 8-15 must stay zero forever)
    for (int e = tid * 4; e < SMEM_T; e += 512 * 4) *(float*)(sm + e) = 0.0f;
    // stage x(t=0), rows 0-7 only
    if (tid < 24) {
        int row = tid / 3, c = tid - row * 3;
        *(float*)(sm + L_X1 + row * 16 + c * 4) = x[(size_t)(Bb + row) * T_SEQ * 3 + c];
    }

    // ---- persistent weight fragments in VGPRs ----
    f16x8 b1h[3][2];               // waves 0-3: w_hh1 [192][64]
    f16x8 b3x[3][4], b3h[3][2];    // waves 4-7: w_ih3 [192][128], w_hh3 [192][64]
    f16x8 b2x[3][2], b2h[3][4];    // all waves: w_ih2 [384][64], w_hh2 [384][128]
    float wi1[9];
    float bs1r = 0, bs1z = 0, bi1n = 0, bh1n = 0;
    float bs3r = 0, bs3z = 0, bi3n = 0, bh3n = 0;

    const int cj = (wv & 3) * 16 + lc;    // h-col for L1/L3 phases
    if (wv < 4) {
        #pragma unroll
        for (int g = 0; g < 3; ++g) {
            #pragma unroll
            for (int kt = 0; kt < 2; ++kt)
                b1h[g][kt] = loadB(w_hh1, g * 64 + cj, 64, kt * 32 + lr * 8);
        }
        bs1r = b_ih1[cj] + b_hh1[cj];
        bs1z = b_ih1[cj + 64] + b_hh1[cj + 64];
        bi1n = b_ih1[cj + 128]; bh1n = b_hh1[cj + 128];
        #pragma unroll
        for (int g = 0; g < 3; ++g)
            #pragma unroll
            for (int i = 0; i < 3; ++i) wi1[g * 3 + i] = w_ih1[(cj + g * 64) * 3 + i];
    } else {
        #pragma unroll
        for (int g = 0; g < 3; ++g) {
            #pragma unroll
            for (int kt = 0; kt < 4; ++kt)
                b3x[g][kt] = loadB(w_ih3, g * 64 + cj, 128, kt * 32 + lr * 8);
            #pragma unroll
            for (int kt = 0; kt < 2; ++kt)
                b3h[g][kt] = loadB(w_hh3, g * 64 + cj, 64, kt * 32 + lr * 8);
        }
        bs3r = b_ih3[cj] + b_hh3[cj];
        bs3z = b_ih3[cj + 64] + b_hh3[cj + 64];
        bi3n = b_ih3[cj + 128]; bh3n = b_hh3[cj + 128];
    }
    const int cj2 = wv * 16 + lc;         // h-col for L2 phase
    #pragma unroll
    for (int g = 0; g < 3; ++g) {
        #pragma unroll
        for (int kt = 0; kt < 2; ++kt)
            b2x[g][kt] = loadB(w_ih2, g * 128 + cj2, 64, kt * 32 + lr * 8);
        #pragma unroll
        for (int kt = 0; kt < 4; ++kt)
            b2h[g][kt] = loadB(w_hh2, g * 128 + cj2, 128, kt * 32 + lr * 8);
    }
    const float bs2r = b_ih2[cj2] + b_hh2[cj2];
    const float bs2z = b_ih2[cj2 + 128] + b_hh2[cj2 + 128];
    const float bi2n = b_ih2[cj2 + 256], bh2n = b_hh2[cj2 + 256];

    // recurrent state in registers (D-frag layout: col=lc, rows lr*4+i)
    float h1o[4] = {0, 0, 0, 0}, h2o[4] = {0, 0, 0, 0}, h3o[4] = {0, 0, 0, 0};
    float accd = 0.0f;

    // dense1 (P4) mapping for this thread: waves 4-7 own jo 0..31 (phase A),
    // waves 0-3 own jo 32..63 (phase C)
    const int p4q  = (wv >= 4) ? (tid - 256) : tid;
    const int p4b  = p4q & 7;
    const int p4jo = (p4q >> 3) + ((wv >= 4) ? 0 : 32);

    int cur = 0;
    #pragma unroll 1
    for (int t = 0; t <= T_SEQ; ++t) {
        const int nxt = cur ^ 1;
        __syncthreads();   // x(t) staged; h*s[cur], H3R[(t-1)&1] complete

        // ================= Phase A =================
        // waves 0-3: layer 1 (t);  waves 4-7: dense1 half (t-1)
        if (wv < 4) {
            if (t < T_SEQ) {
                f16x8 ah0 = ldsA(sm, L_H1S + cur * 2048, 128, lc, lr * 16);
                f16x8 ah1 = ldsA(sm, L_H1S + cur * 2048, 128, lc, 64 + lr * 16);
                f32x4 aR = {0,0,0,0}, aZ = {0,0,0,0}, aN = {0,0,0,0};
                aR = mfma16(ah0, b1h[0][0], aR); aR = mfma16(ah1, b1h[0][1], aR);
                aZ = mfma16(ah0, b1h[1][0], aZ); aZ = mfma16(ah1, b1h[1][1], aZ);
                aN = mfma16(ah0, b1h[2][0], aN); aN = mfma16(ah1, b1h[2][1], aN);
                #pragma unroll
                for (int i = 0; i < 4; ++i) {
                    const int row = lr * 4 + i;
                    float4 xv = *(const float4*)(sm + L_X1 + row * 16);
                    float xgr = wi1[0] * xv.x + wi1[1] * xv.y + wi1[2] * xv.z;
                    float xgz = wi1[3] * xv.x + wi1[4] * xv.y + wi1[5] * xv.z;
                    float xgn = wi1[6] * xv.x + wi1[7] * xv.y + wi1[8] * xv.z;
                    float r = sigm(aR[i] + xgr + bs1r);
                    float z = sigm(aZ[i] + xgz + bs1z);
                    float n = tanh_f((xgn + bi1n) + r * (aN[i] + bh1n));
                    float hv = (1.f - z) * n + z * h1o[i];
                    h1o[i] = hv;
                    if (l < 32) {
                        stH(sm, L_H1S + nxt * 2048, 128, row, cj, (f16)hv);
                        stH(sm, L_H1R, 128, row, cj, (f16)fmaxf(hv, 0.f));
                    }
                }
            }
        } else if (t >= 1) {
            const int rb = (t - 1) & 1;
            #pragma unroll
            for (int i = 0; i < 8; ++i) {
                int off = (L_H3R + rb * 2048 + p4b * 128 + i * 16) ^ ((p4b & 7) << 4);
                f16x8 hv = *(const f16x8*)(sm + off);
                if constexpr (W1H) {
                    f16x8 w8 = *(const f16x8*)(w1h + (size_t)p4jo * (T_SEQ * 64) + (size_t)(t - 1) * 64 + i * 8);
                    accd = dot8(hv, w8, accd);
                } else {
                    const float* wp = w1 + (size_t)p4jo * (T_SEQ * 64) + (size_t)(t - 1) * 64 + i * 8;
                    float4 a = *(const float4*)wp;
                    float4 b = *(const float4*)(wp + 4);
                    accd += (float)hv[0] * a.x + (float)hv[1] * a.y + (float)hv[2] * a.z + (float)hv[3] * a.w
                          + (float)hv[4] * b.x + (float)hv[5] * b.y + (float)hv[6] * b.z + (float)hv[7] * b.w;
                }
            }
        }
        __syncthreads();

        // ================= Phase B: layer 2 (all 8 waves) =================
        if (t < T_SEQ) {
            f16x8 ax0 = ldsA(sm, L_H1R, 128, lc, lr * 16);
            f16x8 ax1 = ldsA(sm, L_H1R, 128, lc, 64 + lr * 16);
            f16x8 ah0 = ldsA(sm, L_H2S + cur * 4096, 256, lc, lr * 16);
            f16x8 ah1 = ldsA(sm, L_H2S + cur * 4096, 256, lc, 64 + lr * 16);
            f16x8 ah2 = ldsA(sm, L_H2S + cur * 4096, 256, lc, 128 + lr * 16);
            f16x8 ah3 = ldsA(sm, L_H2S + cur * 4096, 256, lc, 192 + lr * 16);
            f32x4 aR = {0,0,0,0}, aZ = {0,0,0,0}, aXn = {0,0,0,0}, aHn = {0,0,0,0};
            aR = mfma16(ax0, b2x[0][0], aR); aR = mfma16(ax1, b2x[0][1], aR);
            aR = mfma16(ah0, b2h[0][0], aR); aR = mfma16(ah1, b2h[0][1], aR);
            aR = mfma16(ah2, b2h[0][2], aR); aR = mfma16(ah3, b2h[0][3], aR);
            aZ = mfma16(ax0, b2x[1][0], aZ); aZ = mfma16(ax1, b2x[1][1], aZ);
            aZ = mfma16(ah0, b2h[1][0], aZ); aZ = mfma16(ah1, b2h[1][1], aZ);
            aZ = mfma16(ah2, b2h[1][2], aZ); aZ = mfma16(ah3, b2h[1][3], aZ);
            aXn = mfma16(ax0, b2x[2][0], aXn); aXn = mfma16(ax1, b2x[2][1], aXn);
            aHn = mfma16(ah0, b2h[2][0], aHn); aHn = mfma16(ah1, b2h[2][1], aHn);
            aHn = mfma16(ah2, b2h[2][2], aHn); aHn = mfma16(ah3, b2h[2][3], aHn);
            #pragma unroll
            for (int i = 0; i < 4; ++i) {
                const int row = lr * 4 + i;
                float r = sigm(aR[i] + bs2r);
                float z = sigm(aZ[i] + bs2z);
                float n = tanh_f((aXn[i] + bi2n) + r * (aHn[i] + bh2n));
                float hv = (1.f - z) * n + z * h2o[i];
                h2o[i] = hv;
                if (l < 32) {
                    stH(sm, L_H2S + nxt * 4096, 256, row, cj2, (f16)hv);
                    stH(sm, L_H2R, 256, row, cj2, (f16)fmaxf(hv, 0.f));
                }
            }
        }
        __syncthreads();

        // ================= Phase C =================
        // waves 4-7: layer 3 (t);  waves 0-3: dense1 half (t-1) + x prefetch
        if (wv >= 4) {
            if (t < T_SEQ) {
                f16x8 ax0 = ldsA(sm, L_H2R, 256, lc, lr * 16);
                f16x8 ax1 = ldsA(sm, L_H2R, 256, lc, 64 + lr * 16);
                f16x8 ax2 = ldsA(sm, L_H2R, 256, lc, 128 + lr * 16);
                f16x8 ax3 = ldsA(sm, L_H2R, 256, lc, 192 + lr * 16);
                f16x8 ah0 = ldsA(sm, L_H3S + cur * 2048, 128, lc, lr * 16);
                f16x8 ah1 = ldsA(sm, L_H3S + cur * 2048, 128, lc, 64 + lr * 16);
                f32x4 aR = {0,0,0,0}, aZ = {0,0,0,0}, aXn = {0,0,0,0}, aHn = {0,0,0,0};
                aR = mfma16(ax0, b3x[0][0], aR); aR = mfma16(ax1, b3x[0][1], aR);
                aR = mfma16(ax2, b3x[0][2], aR); aR = mfma16(ax3, b3x[0][3], aR);
                aR = mfma16(ah0, b3h[0][0], aR); aR = mfma16(ah1, b3h[0][1], aR);
                aZ = mfma16(ax0, b3x[1][0], aZ); aZ = mfma16(ax1, b3x[1][1], aZ);
                aZ = mfma16(ax2, b3x[1][2], aZ); aZ = mfma16(ax3, b3x[1][3], aZ);
                aZ = mfma16(ah0, b3h[1][0], aZ); aZ = mfma16(ah1, b3h[1][1], aZ);
                aXn = mfma16(ax0, b3x[2][0], aXn); aXn = mfma16(ax1, b3x[2][1], aXn);
                aXn = mfma16(ax2, b3x[2][2], aXn); aXn = mfma16(ax3, b3x[2][3], aXn);
                aHn = mfma16(ah0, b3h[2][0], aHn); aHn = mfma16(ah1, b3h[2][1], aHn);
                #pragma unroll
                for (int i = 0; i < 4; ++i) {
                    const int row = lr * 4 + i;
                    float r = sigm(aR[i] + bs3r);
                    float z = sigm(aZ[i] + bs3z);
                    float n = tanh_f((aXn[i] + bi3n) + r * (aHn[i] + bh3n));
                    float hv = (1.f - z) * n + z * h3o[i];
                    h3o[i] = hv;
                    if (l < 32) {
                        stH(sm, L_H3S + nxt * 2048, 128, row, cj, (f16)hv);
                        stH(sm, L_H3R + (t & 1) * 2048, 128, row, cj, (f16)fmaxf(hv, 0.f));
                    }
                }
            }
        } else {
            if (t >= 1) {
                const int rb = (t - 1) & 1;
                #pragma unroll
                for (int i = 0; i < 8; ++i) {
                    int off = (L_H3R + rb * 2048 + p4b * 128 + i * 16) ^ ((p4b & 7) << 4);
                    f16x8 hv = *(const f16x8*)(sm + off);
                    if constexpr (W1H) {
                        f16x8 w8 = *(const f16x8*)(w1h + (size_t)p4jo * (T_SEQ * 64) + (size_t)(t - 1) * 64 + i * 8);
                        accd = dot8(hv, w8, accd);
                    } else {
                        const float* wp = w1 + (size_t)p4jo * (T_SEQ * 64) + (size_t)(t - 1) * 64 + i * 8;
                        float4 a = *(const float4*)wp;
                        float4 b = *(const float4*)(wp + 4);
                        accd += (float)hv[0] * a.x + (float)hv[1] * a.y + (float)hv[2] * a.z + (float)hv[3] * a.w
                              + (float)hv[4] * b.x + (float)hv[5] * b.y + (float)hv[6] * b.z + (float)hv[7] * b.w;
                    }
                }
            }
            if (t + 1 < T_SEQ && tid < 24) {
                int row = tid / 3, c = tid - row * 3;
                *(float*)(sm + L_X1 + row * 16 + c * 4) =
                    x[(size_t)(Bb + row) * T_SEQ * 3 + (size_t)(t + 1) * 3 + c];
            }
        }
        if (t < T_SEQ) cur ^= 1;
    }

    // ---------- head: dense1 bias+relu -> dense2 -> dense3 ----------
    __syncthreads();
    float* o1 = (float*)sm;              // [8][68]
    o1[p4b * 68 + p4jo] = fmaxf(accd + bd1[p4jo], 0.f);
    __syncthreads();
    float* o2 = (float*)(sm + 4096);     // [8][36]
    if (tid < 256) {
        const int bb = tid & 7, m = tid >> 3;
        float acc = bd2[m];
        const float* w2p = w2 + m * 64;
        const float* o1p = o1 + bb * 68;
        #pragma unroll
        for (int i = 0; i < 16; ++i) {
            float4 a = *(const float4*)(o1p + i * 4);
            float4 wv8 = *(const float4*)(w2p + i * 4);
            acc += a.x * wv8.x + a.y * wv8.y + a.z * wv8.z + a.w * wv8.w;
        }
        o2[bb * 36 + m] = fmaxf(acc, 0.f);
    }
    __syncthreads();
    for (int e = tid; e < 8 * 250; e += 512) {
        const int bb = e / 250, p = e - bb * 250;
        float acc = bd3[p];
        const float* w3p = w3 + p * 32;
        const float* o2p = o2 + bb * 36;
        #pragma unroll
        for (int i = 0; i < 8; ++i) {
            float4 a = *(const float4*)(o2p + i * 4);
            float4 wv8 = *(const float4*)(w3p + i * 4);
            acc += a.x * wv8.x + a.y * wv8.y + a.z * wv8.z + a.w * wv8.w;
        }
        out[(size_t)(Bb + bb) * 250 + p] = fmaxf(acc, 0.f);
    }
}

extern "C" void kernel_launch(void* const* d_in, const int* in_sizes, int n_in,
                              void* d_out, int out_size, void* d_ws, size_t ws_size,
                              hipStream_t stream) {
    const float* x     = (const float*)d_in[0];
    const float* w_ih1 = (const float*)d_in[1];
    const float* w_hh1 = (const float*)d_in[2];
    const float* b_ih1 = (const float*)d_in[3];
    const float* b_hh1 = (const float*)d_in[4];
    const float* w_ih2 = (const float*)d_in[5];
    const float* w_hh2 = (const float*)d_in[6];
    const float* b_ih2 = (const float*)d_in[7];
    const float* b_hh2 = (const float*)d_in[8];
    const float* w_ih3 = (const float*)d_in[9];
    const float* w_hh3 = (const float*)d_in[10];
    const float* b_ih3 = (const float*)d_in[11];
    const float* b_hh3 = (const float*)d_in[12];
    const float* w1    = (const float*)d_in[13];
    const float* bd1   = (const float*)d_in[14];
    const float* w2    = (const float*)d_in[15];
    const float* bd2   = (const float*)d_in[16];
    const float* w3    = (const float*)d_in[17];
    const float* bd3   = (const float*)d_in[18];
    float* out = (float*)d_out;

    const int n1 = 64 * T_SEQ * 64;                 // w1 elements
    const bool useF16 = ws_size >= (size_t)n1 * sizeof(f16);
    f16* w1h = (f16*)d_ws;

    if (useF16) {
        hipLaunchKernelGGL(cvt_f16, dim3((n1 + 255) / 256), dim3(256), 0, stream, w1, w1h, n1);
        hipLaunchKernelGGL((gru_fused<true>), dim3(B_TOT / 8), dim3(512), 0, stream,
                           x, w_ih1, w_hh1, b_ih1, b_hh1, w_ih2, w_hh2, b_ih2, b_hh2,
                           w_ih3, w_hh3, b_ih3, b_hh3,
                           w1h, w1, bd1, w2, bd2, w3, bd3, out);
    } else {
        hipLaunchKernelGGL((gru_fused<false>), dim3(B_TOT / 8), dim3(512), 0, stream,
                           x, w_ih1, w_hh1, b_ih1, b_hh1, w_ih2, w_hh2, b_ih2, b_hh2,
                           w_ih3, w_hh3, b_ih3, b_hh3,
                           w1h, w1, bd1, w2, bd2, w3, bd3, out);
    }
}